// Round 2
// baseline (508.630 us; speedup 1.0000x reference)
//
#include <hip/hip_runtime.h>
#include <hip/hip_bf16.h>
#include <stdint.h>

#define T_    16
#define N_    32
#define C_    128
#define HW_   1024
#define COUT_ 128

typedef __bf16 bf16x8 __attribute__((ext_vector_type(8)));
typedef float  f32x4  __attribute__((ext_vector_type(4)));

// ---------------- K0: prep pw weights (bf16) + BN epilogue constants ----------------
__global__ __launch_bounds__(256) void k0_prep(
    const float* __restrict__ pw_w, const float* __restrict__ pw_b,
    const float* __restrict__ gamma, const float* __restrict__ beta,
    const float* __restrict__ mean,  const float* __restrict__ var,
    __bf16* __restrict__ wbf, float* __restrict__ scale2, float* __restrict__ bias2) {
  int idx = blockIdx.x * 256 + threadIdx.x;
  if (idx < COUT_ * C_) wbf[idx] = (__bf16)pw_w[idx];
  if (idx < COUT_) {
    float s = gamma[idx] * rsqrtf(var[idx] + 1e-5f);
    scale2[idx] = s;
    bias2[idx]  = beta[idx] + (pw_b[idx] - mean[idx]) * s;
  }
}

// spread bit i -> bit 4i (i in [0,8))
__device__ __forceinline__ uint32_t spread4(uint32_t x) {
  x = (x | (x << 12)) & 0x000F000Fu;
  x = (x | (x << 6))  & 0x03030303u;
  x = (x | (x << 3))  & 0x11111111u;
  return x;
}

// ---------------- K1 v2: LIF scan -> packed spike bits ----------------
// block = one (n,c). Thread tid owns pixels [4*tid, 4*tid+4): ONE f32x4 load per t
// (16 B/lane, wave covers 1 KiB contiguous). Spike bits re-assembled into spatial-order
// 32-bit row words via 4 ballots + bit-spread; 8 lanes/wave store 8 consecutive words.
// S layout identical to v1: word[((n*128+c)*16 + t)*32 + row] = 32 col-bits of that row.
__global__ __launch_bounds__(256) void k1_lif(const float* __restrict__ x,
                                              uint32_t* __restrict__ S) {
  const int nc   = blockIdx.x;          // n*128 + c
  const int tid  = threadIdx.x;
  const int lane = tid & 63;
  const int w    = tid >> 6;
  const size_t img = (size_t)N_ * C_ * HW_;
  const float* xb = x + (size_t)nc * HW_ + (size_t)tid * 4;
  const int r8 = (lane & 7) * 8;

  f32x4 xv = *(const f32x4*)xb;          // prefetch t=0
  float v0 = 0.f, v1 = 0.f, v2 = 0.f, v3 = 0.f;
#pragma unroll
  for (int t = 0; t < T_; ++t) {
    f32x4 cx = xv;
    if (t < T_ - 1) xv = *(const f32x4*)(xb + img * (size_t)(t + 1));
    // v <- v + (x - v)/2 ; spike = (v >= 1) ; v <- spiked ? 0 : v
    v0 = v0 + (cx[0] - v0) * 0.5f; bool s0 = (v0 >= 1.0f); if (s0) v0 = 0.f;
    v1 = v1 + (cx[1] - v1) * 0.5f; bool s1 = (v1 >= 1.0f); if (s1) v1 = 0.f;
    v2 = v2 + (cx[2] - v2) * 0.5f; bool s2 = (v2 >= 1.0f); if (s2) v2 = 0.f;
    v3 = v3 + (cx[3] - v3) * 0.5f; bool s3 = (v3 >= 1.0f); if (s3) v3 = 0.f;
    // m_j bit l = spike of pixel 256*w + 4*l + j
    uint64_t m0 = __ballot(s0);
    uint64_t m1 = __ballot(s1);
    uint64_t m2 = __ballot(s2);
    uint64_t m3 = __ballot(s3);
    // row (8w + r), r = lane&7: word bit 4i+j = byte r of m_j, bit i
    uint32_t b0 = (uint32_t)(m0 >> r8) & 0xffu;
    uint32_t b1 = (uint32_t)(m1 >> r8) & 0xffu;
    uint32_t b2 = (uint32_t)(m2 >> r8) & 0xffu;
    uint32_t b3 = (uint32_t)(m3 >> r8) & 0xffu;
    uint32_t word = spread4(b0) | (spread4(b1) << 1) | (spread4(b2) << 2) | (spread4(b3) << 3);
    if (lane < 8)
      S[((size_t)nc * T_ + t) * 32 + w * 8 + lane] = word;   // 32 B dense per wave
  }
}

// ---------------- K2 v2: bits -> depthwise (VALU) -> LDS B tile -> MFMA -> BN -> out ----
// block: one (n_img, row-group of 4 rows => 128 hw). 256 threads = 4 waves.
// Epilogue transposes acc through LDS and stores f32x4 (two full 512 B rows / inst).
__global__ __launch_bounds__(256) void k2_main(
    const uint32_t* __restrict__ S,
    const float* __restrict__ dww, const float* __restrict__ dwb,
    const __bf16* __restrict__ wbf,
    const float* __restrict__ scale2, const float* __restrict__ bias2,
    float* __restrict__ out) {
  // smem union: [sb 4 KB][Blds 34816 B] ; epilogue reuses the whole thing as F[64][132] f32
  __shared__ __align__(16) char smem[4096 + 128 * 136 * 2];
  uint32_t* sb  = (uint32_t*)smem;          // [c][8] (6 used)
  __bf16*  Blds = (__bf16*)(smem + 4096);   // [hw local 0..127][c], pitch 136
  float*   F    = (float*)smem;             // epilogue: [64 o-rows][132]

  const int bid   = blockIdx.x;
  const int n_img = bid >> 3;              // t*N + n
  const int rg    = bid & 7;
  const int t_img = n_img >> 5;            // / N_
  const int n_in  = n_img & 31;
  const int r0    = rg * 4;
  const int tid   = threadIdx.x;

  // ---- Phase A: stage 128c x 6 spike row-words into LDS ----
#pragma unroll
  for (int k = 0; k < 3; ++k) {
    int li = k * 256 + tid;                // 0..767 = c*6 + ri
    int c  = li / 6;
    int ri = li - c * 6;
    int gr = r0 - 1 + ri;
    uint32_t wv = 0;
    if (gr >= 0 && gr < 32)
      wv = S[(((size_t)n_in * C_ + c) * T_ + t_img) * 32 + gr];
    sb[c * 8 + ri] = wv;
  }
  __syncthreads();

  // ---- Phase B: depthwise 3x3 from bits -> bf16 B tile [hw][c] ----
  {
    int c    = tid & 127;
    int half = tid >> 7;                    // wave-uniform
    float w9[9];
#pragma unroll
    for (int i = 0; i < 9; ++i) w9[i] = dww[c * 9 + i];
    float bias = dwb[c];
    uint64_t R[6];
#pragma unroll
    for (int q = 0; q < 6; ++q) R[q] = ((uint64_t)sb[c * 8 + q]) << 1;

    int col0 = half * 16;
#pragma unroll 4
    for (int ci = 0; ci < 16; ++ci) {
      int col = col0 + ci;
      float acc4[4] = {bias, bias, bias, bias};
#pragma unroll
      for (int q = 0; q < 6; ++q) {
        uint32_t tri = (uint32_t)(R[q] >> col) & 7u;  // bits col-1,col,col+1 (zero-padded)
        float b0 = (float)(tri & 1u);
        float b1 = (float)((tri >> 1) & 1u);
        float b2 = (float)(tri >> 2);
#pragma unroll
        for (int kh = 0; kh < 3; ++kh) {
          int r = q - kh;                   // source row q = r + kh
          if (r >= 0 && r < 4) {
            acc4[r] += w9[kh * 3 + 0] * b0;
            acc4[r] += w9[kh * 3 + 1] * b1;
            acc4[r] += w9[kh * 3 + 2] * b2;
          }
        }
      }
#pragma unroll
      for (int r = 0; r < 4; ++r)
        Blds[(r * 32 + col) * 136 + c] = (__bf16)acc4[r];
    }
  }
  __syncthreads();

  // ---- Phase C: GEMM  out[o, hw] = sum_c pw[o,c] * B[c, hw], 4 waves: 2x2 of 64x64 ----
  const int lane  = tid & 63;
  const int wid   = tid >> 6;
  const int ohalf = wid >> 1;
  const int hhalf = wid & 1;
  const int m16   = lane & 15;
  const int q4    = lane >> 4;

  f32x4 acc[4][4];
#pragma unroll
  for (int mt = 0; mt < 4; ++mt)
#pragma unroll
    for (int nt = 0; nt < 4; ++nt)
      acc[mt][nt] = (f32x4){0.f, 0.f, 0.f, 0.f};

#pragma unroll
  for (int ks = 0; ks < 4; ++ks) {
    const int k0 = ks * 32 + q4 * 8;
    bf16x8 af[4], bfr[4];
#pragma unroll
    for (int mt = 0; mt < 4; ++mt) {
      int m = ohalf * 64 + mt * 16 + m16;
      af[mt] = *(const bf16x8*)(wbf + m * 128 + k0);
    }
#pragma unroll
    for (int nt = 0; nt < 4; ++nt) {
      int hw = hhalf * 64 + nt * 16 + m16;
      bfr[nt] = *(const bf16x8*)(Blds + hw * 136 + k0);
    }
#pragma unroll
    for (int nt = 0; nt < 4; ++nt)
#pragma unroll
      for (int mt = 0; mt < 4; ++mt)
        acc[mt][nt] = __builtin_amdgcn_mfma_f32_16x16x32_bf16(af[mt], bfr[nt], acc[mt][nt], 0, 0, 0);
  }

  __syncthreads();   // Blds reads complete; smem reusable as F

  // ---- Epilogue v2: BN fold -> LDS transpose -> f32x4 stores (512 B row segments) ----
  const size_t outbase = (size_t)n_img * (COUT_ * HW_) + (size_t)rg * 128;
  const int rrow = tid >> 5;               // 0..7
  const int cw   = (tid & 31) * 4;         // hw chunk
#pragma unroll
  for (int g = 0; g < 2; ++g) {
    if (ohalf == g) {
#pragma unroll
      for (int mt = 0; mt < 4; ++mt) {
        int orow = mt * 16 + q4 * 4;       // row within this 64-row group
        int ob   = g * 64 + orow;          // global output channel base
        f32x4 sc = *(const f32x4*)(scale2 + ob);
        f32x4 bs = *(const f32x4*)(bias2 + ob);
#pragma unroll
        for (int nt = 0; nt < 4; ++nt) {
          int hw = hhalf * 64 + nt * 16 + m16;
#pragma unroll
          for (int ri = 0; ri < 4; ++ri)
            F[(orow + ri) * 132 + hw] = acc[mt][nt][ri] * sc[ri] + bs[ri];
        }
      }
    }
    __syncthreads();
#pragma unroll
    for (int i = 0; i < 8; ++i) {
      int orow = i * 8 + rrow;
      f32x4 val = *(const f32x4*)(F + orow * 132 + cw);
      *(f32x4*)(out + outbase + (size_t)(g * 64 + orow) * HW_ + cw) = val;
    }
    if (g == 0) __syncthreads();
  }
}

// ---------------- launcher ----------------
extern "C" void kernel_launch(void* const* d_in, const int* in_sizes, int n_in_args,
                              void* d_out, int out_size, void* d_ws, size_t ws_size,
                              hipStream_t stream) {
  const float* x     = (const float*)d_in[0];
  const float* dw_w  = (const float*)d_in[1];
  const float* dw_b  = (const float*)d_in[2];
  const float* pw_w  = (const float*)d_in[3];
  const float* pw_b  = (const float*)d_in[4];
  const float* gamma = (const float*)d_in[5];
  const float* beta  = (const float*)d_in[6];
  const float* rmean = (const float*)d_in[7];
  const float* rvar  = (const float*)d_in[8];
  float* out = (float*)d_out;

  // ws layout: spikes 8 MB | wbf16 32 KB | scale2 512 B | bias2 512 B
  uint32_t* S    = (uint32_t*)d_ws;
  __bf16* wbf    = (__bf16*)((char*)d_ws + (size_t)N_ * C_ * T_ * 128);
  float* scale2  = (float*)((char*)wbf + (size_t)COUT_ * C_ * 2);
  float* bias2   = scale2 + COUT_;

  k0_prep<<<64, 256, 0, stream>>>(pw_w, pw_b, gamma, beta, rmean, rvar, wbf, scale2, bias2);
  k1_lif<<<N_ * C_, 256, 0, stream>>>(x, S);
  k2_main<<<(T_ * N_) * 8, 256, 0, stream>>>(S, dw_w, dw_b, wbf, scale2, bias2, out);
}